// Round 7
// baseline (272.584 us; speedup 1.0000x reference)
//
#include <hip/hip_runtime.h>
#include <hip/hip_bf16.h>
#include <stdint.h>

typedef __attribute__((ext_vector_type(8))) short short8;
typedef __attribute__((ext_vector_type(4))) float f32x4;
typedef __attribute__((ext_vector_type(4))) unsigned short ushort4_t;

#define SEG 16

__device__ __forceinline__ float bf2f(unsigned short u) {
  unsigned int x = ((unsigned int)u) << 16;
  return __uint_as_float(x);
}
__device__ __forceinline__ unsigned short f2bf(float f) {
  unsigned int u = __float_as_uint(f);
  u += 0x7fffu + ((u >> 16) & 1u);
  return (unsigned short)(u >> 16);
}

// async global->LDS, 16B per lane, dest = wave-uniform base + lane*16
__device__ __forceinline__ void gload16(const unsigned short* g, unsigned short* l) {
  __builtin_amdgcn_global_load_lds(
      (const __attribute__((address_space(1))) void*)g,
      (__attribute__((address_space(3))) void*)l, 16, 0, 0);
}

// ---------------- cast fp32 -> bf16 (vectorized) ----------------
__global__ void cast_f32_bf16(const float* __restrict__ in,
                              unsigned short* __restrict__ out, int n4) {
  const int stride = gridDim.x * blockDim.x;
  for (int i = blockIdx.x * blockDim.x + threadIdx.x; i < n4; i += stride) {
    const float4 v = ((const float4*)in)[i];
    ushort4_t o;
    o[0] = f2bf(v.x); o[1] = f2bf(v.y); o[2] = f2bf(v.z); o[3] = f2bf(v.w);
    ((ushort4_t*)out)[i] = o;
  }
}

// ======== GEMM v4: 256x128, BK=32, triple-buffer, 1 barrier/tile, 2 blk/CU ====
// C[M,N] = A[M,K] * B[N,K]^T. 512 thr = 8 waves (4M x 2N), wave-out 64x64.
// LDS 72KB: 3 slots x (A[256][32] 16KB + B[128][32] 8KB) -> 2 blocks/CU
// (144KB LDS, ~120 unified regs = 4 waves/SIMD).
// Schedule (R6 post-mortem): during tile t stage tile t+2 into slot (t+2)%3;
// single {vmcnt(3); s_barrier} per tile. Tile t+1's loads were issued at t-1,
// two full tiles before use -> latency fully hidden; never drain to 0.
// Race proof: slot(t+2)%3 last read at t-1, separated by end-of-(t-1) barrier
// (ds_reads consumed by MFMAs pre-barrier). vmcnt(3) at end-of-t leaves only
// own t+2 stages outstanding -> everything older (incl. t+1's) complete.
// Swizzle: LDS[r][chunk p] = G[r][p ^ swz(r)], swz(r)=(r&3)^((r>>2)&1):
// per-16-row fragment read -> 8 distinct banks, uniform 2-way (free, m136).
template <typename OutT>
__global__ __launch_bounds__(512, 4) void gemm_v4(
    const unsigned short* __restrict__ A, const unsigned short* __restrict__ Bm,
    OutT* __restrict__ C, int M, int N, int K, int ldc, int fm_cols) {
  __shared__ unsigned short lds[3 * 12288];  // slot: A @0 (8192 el), B @8192 (4096 el)
  const int tid = threadIdx.x;
  const int lane = tid & 63;
  const int w = tid >> 6;
  const int wr = w >> 1, wc = w & 1;  // 4x2 wave grid; wave out = 64x64
  // XCD-aware bijective swizzle (nwg % 8 == 0 for all our grids)
  const int gx = gridDim.x;
  const int nwg = gx * gridDim.y;
  const int hwid = blockIdx.y * gx + blockIdx.x;
  const int cpx = nwg >> 3;
  const int L = (hwid & 7) * cpx + (hwid >> 3);
  const int bx = L % gx, by = L / gx;
  const size_t arow0 = (size_t)by * 256;
  const size_t bcol0 = (size_t)bx * 128;
  const int nt = K >> 5;  // BK=32

  // staging: one gload16 covers 16 rows x 32 elems; lane l: row=l>>2, chunk=l&3
  const int rl = lane >> 2;
  const int sce = (((lane & 3) ^ (rl & 3) ^ ((rl >> 2) & 1)) << 3);  // pre-swizzled src
  const unsigned short* Ab0 = A + (arow0 + w * 16 + rl) * K + sce;
  const unsigned short* Ab1 = A + (arow0 + 128 + w * 16 + rl) * K + sce;
  const unsigned short* Bb0 = Bm + (bcol0 + w * 16 + rl) * K + sce;

  auto stage = [&](int kt, unsigned short* buf) {
    const int k0 = (kt < nt ? kt : kt - nt) << 5;  // wrap = harmless dummy restage
    gload16(Ab0 + k0, buf + w * 512);
    gload16(Ab1 + k0, buf + 4096 + w * 512);
    gload16(Bb0 + k0, buf + 8192 + w * 512);
  };

  f32x4 acc[4][4] = {};
  const int fr = lane & 15;  // fragment row/col
  const int kc = lane >> 4;  // K-octet 0..3

  auto rdA = [&](const unsigned short* buf, int mm) {
    const int r = wr * 64 + mm * 16 + fr;
    return *(const short8*)&buf[r * 32 + ((kc ^ (fr & 3) ^ ((fr >> 2) & 1)) << 3)];
  };
  auto rdB = [&](const unsigned short* buf, int nn) {
    const int r = wc * 64 + nn * 16 + fr;
    return *(const short8*)&buf[8192 + r * 32 + ((kc ^ (fr & 3) ^ ((fr >> 2) & 1)) << 3)];
  };

  // prologue: tiles 0,1 -> slots 0,1; wait for tile 0 (leave tile 1 in flight)
  stage(0, lds);
  stage(1, lds + 12288);
  asm volatile("s_waitcnt vmcnt(3)" ::: "memory");
  __builtin_amdgcn_s_barrier();
  __builtin_amdgcn_sched_barrier(0);

  for (int t = 0; t < nt; ++t) {
    const unsigned short* cur = lds + (t % 3) * 12288;
    unsigned short* nxt = lds + ((t + 2) % 3) * 12288;
    stage(t + 2, nxt);
    const short8 af0 = rdA(cur, 0), af1 = rdA(cur, 1), af2 = rdA(cur, 2), af3 = rdA(cur, 3);
    const short8 bf0 = rdB(cur, 0), bf1 = rdB(cur, 1), bf2 = rdB(cur, 2), bf3 = rdB(cur, 3);
    __builtin_amdgcn_s_setprio(1);
    acc[0][0] = __builtin_amdgcn_mfma_f32_16x16x32_bf16(af0, bf0, acc[0][0], 0, 0, 0);
    acc[0][1] = __builtin_amdgcn_mfma_f32_16x16x32_bf16(af0, bf1, acc[0][1], 0, 0, 0);
    acc[1][0] = __builtin_amdgcn_mfma_f32_16x16x32_bf16(af1, bf0, acc[1][0], 0, 0, 0);
    acc[1][1] = __builtin_amdgcn_mfma_f32_16x16x32_bf16(af1, bf1, acc[1][1], 0, 0, 0);
    acc[0][2] = __builtin_amdgcn_mfma_f32_16x16x32_bf16(af0, bf2, acc[0][2], 0, 0, 0);
    acc[0][3] = __builtin_amdgcn_mfma_f32_16x16x32_bf16(af0, bf3, acc[0][3], 0, 0, 0);
    acc[1][2] = __builtin_amdgcn_mfma_f32_16x16x32_bf16(af1, bf2, acc[1][2], 0, 0, 0);
    acc[1][3] = __builtin_amdgcn_mfma_f32_16x16x32_bf16(af1, bf3, acc[1][3], 0, 0, 0);
    acc[2][0] = __builtin_amdgcn_mfma_f32_16x16x32_bf16(af2, bf0, acc[2][0], 0, 0, 0);
    acc[2][1] = __builtin_amdgcn_mfma_f32_16x16x32_bf16(af2, bf1, acc[2][1], 0, 0, 0);
    acc[3][0] = __builtin_amdgcn_mfma_f32_16x16x32_bf16(af3, bf0, acc[3][0], 0, 0, 0);
    acc[3][1] = __builtin_amdgcn_mfma_f32_16x16x32_bf16(af3, bf1, acc[3][1], 0, 0, 0);
    acc[2][2] = __builtin_amdgcn_mfma_f32_16x16x32_bf16(af2, bf2, acc[2][2], 0, 0, 0);
    acc[2][3] = __builtin_amdgcn_mfma_f32_16x16x32_bf16(af2, bf3, acc[2][3], 0, 0, 0);
    acc[3][2] = __builtin_amdgcn_mfma_f32_16x16x32_bf16(af3, bf2, acc[3][2], 0, 0, 0);
    acc[3][3] = __builtin_amdgcn_mfma_f32_16x16x32_bf16(af3, bf3, acc[3][3], 0, 0, 0);
    __builtin_amdgcn_s_setprio(0);
    asm volatile("s_waitcnt vmcnt(3)" ::: "memory");
    __builtin_amdgcn_s_barrier();
    __builtin_amdgcn_sched_barrier(0);
  }

  // epilogue: C/D layout col=lane&15, row=(lane>>4)*4+j  [verified m89/m91]
  const int qq = lane >> 4;
#pragma unroll
  for (int m = 0; m < 4; ++m) {
#pragma unroll
    for (int n = 0; n < 4; ++n) {
      const int col = (int)bcol0 + wc * 64 + n * 16 + fr;
      const bool dofm = col < fm_cols;
#pragma unroll
      for (int j = 0; j < 4; ++j) {
        const int row = (int)arow0 + wr * 64 + m * 16 + qq * 4 + j;
        float x = acc[m][n][j];
        if (dofm) x = (x > 0.f) ? x + 1.f : __expf(x);
        if constexpr (sizeof(OutT) == 2) {
          C[(size_t)row * ldc + col] = (OutT)f2bf(x);
        } else {
          C[(size_t)row * ldc + col] = x;
        }
      }
    }
  }
}

// ---------------- kv state partials: kv[bh,d,e] = sum_n k[n,d]*v[n,e] ----------------
// kvmat: [16384 rows][2048]: cols 0..1023 = fm(k), 1024..2047 = v
__global__ __launch_bounds__(256) void kv_partial(
    const unsigned short* __restrict__ kvmat, float* __restrict__ kvp,
    float* __restrict__ ksp) {
  const int blk = blockIdx.x;      // 64*SEG
  const int bh = blk >> 4;
  const int seg = blk & (SEG - 1);
  const int b = bh >> 4, h = bh & 15;
  const int rows = 4096 / SEG;     // 256
  const size_t row0 = (size_t)b * 4096 + (size_t)seg * rows;
  const unsigned short* kb = kvmat + row0 * 2048 + h * 64;
  const unsigned short* vb = kvmat + row0 * 2048 + 1024 + h * 64;
  __shared__ float kl[32][64];
  __shared__ float vl[32][64];
  const int tid = threadIdx.x;
  const int d0 = (tid >> 4) * 4, e0 = (tid & 15) * 4;
  const int lr = tid >> 3, lc = (tid & 7) * 8;
  float accm[4][4] = {};
  float ksacc[4] = {0.f, 0.f, 0.f, 0.f};

  for (int c = 0; c < rows; c += 32) {
    __syncthreads();
    {
      const short8 k8 = *(const short8*)(kb + (size_t)(c + lr) * 2048 + lc);
      const short8 v8 = *(const short8*)(vb + (size_t)(c + lr) * 2048 + lc);
#pragma unroll
      for (int j = 0; j < 8; ++j) {
        kl[lr][lc + j] = bf2f((unsigned short)k8[j]);
        vl[lr][lc + j] = bf2f((unsigned short)v8[j]);
      }
    }
    __syncthreads();
#pragma unroll
    for (int r = 0; r < 32; ++r) {
      const f32x4 kd = *(const f32x4*)&kl[r][d0];
      const f32x4 ve = *(const f32x4*)&vl[r][e0];
#pragma unroll
      for (int i = 0; i < 4; ++i) {
        ksacc[i] += kd[i];
#pragma unroll
        for (int j = 0; j < 4; ++j) accm[i][j] += kd[i] * ve[j];
      }
    }
  }
  float* kvout = kvp + ((size_t)seg * 64 + bh) * 4096;
#pragma unroll
  for (int i = 0; i < 4; ++i) {
    f32x4 o = {accm[i][0], accm[i][1], accm[i][2], accm[i][3]};
    *(f32x4*)&kvout[(d0 + i) * 64 + e0] = o;
  }
  if ((tid & 15) == 0) {
#pragma unroll
    for (int i = 0; i < 4; ++i)
      ksp[((size_t)seg * 64 + bh) * 64 + d0 + i] = ksacc[i];
  }
}

// reduce partials -> kvb[bh][80][64] bf16: rows e<64 = kv^T, row 64 = ksum, 65..79 = 0
__global__ void kv_reduce_bf(const float* __restrict__ kvp, const float* __restrict__ ksp,
                             unsigned short* __restrict__ kvb) {
  const int idx = blockIdx.x * 256 + threadIdx.x;  // 64*80*64
  if (idx >= 64 * 80 * 64) return;
  const int bh = idx / 5120, r = idx % 5120, e = r >> 6, d = r & 63;
  float s = 0.f;
  if (e < 64) {
    for (int g = 0; g < SEG; ++g) s += kvp[((size_t)g * 64 + bh) * 4096 + d * 64 + e];
  } else if (e == 64) {
    for (int g = 0; g < SEG; ++g) s += ksp[((size_t)g * 64 + bh) * 64 + d];
  }
  kvb[idx] = f2bf(s);
}

// ---------------- attn via MFMA: att[row, h*64+e] = (q.kv)/(q.ksum + 1e-6) ----------------
__global__ __launch_bounds__(256) void attn_mfma(
    const unsigned short* __restrict__ q,    // [16384][1024] bf16 (fm applied)
    const unsigned short* __restrict__ kvb,  // [64][80][64] bf16
    unsigned short* __restrict__ att) {      // [16384][1024] bf16
  const int bh = blockIdx.x >> 4;
  const int rt = blockIdx.x & 15;
  const int b = bh >> 4, h = bh & 15;
  __shared__ unsigned short As[2 * 256 * 32];  // [ks][row][32]  32KB
  __shared__ unsigned short Bs[2 * 80 * 32];   // [ks][e][32]    10KB
  const int tid = threadIdx.x, lane = tid & 63, wave = tid >> 6;
  const int l4 = lane >> 2;
  const int c8 = (lane & 3) * 8;
  const size_t qrow0 = (size_t)b * 4096 + (size_t)rt * 256;
  const unsigned short* Ab = q + (qrow0 + wave * 64 + l4) * 1024 + h * 64 + c8;
  unsigned short* AsW = As;
#pragma unroll
  for (int ks = 0; ks < 2; ++ks)
#pragma unroll
    for (int i = 0; i < 4; ++i)
      gload16(Ab + (size_t)i * 16 * 1024 + ks * 32,
              AsW + ks * 8192 + wave * 2048 + i * 512);
  for (int c = tid; c < 640; c += 256) {
    const int m0 = c * 8, ks = m0 / 2560, rr = m0 % 2560, e = rr / 32, dk = rr % 32;
    *(short8*)&Bs[m0] = *(const short8*)&kvb[(size_t)bh * 5120 + e * 64 + ks * 32 + dk];
  }
  __syncthreads();

  const int fr = lane & 15, ko = (lane >> 4) * 8;
  short8 af[4][2], bfv[5][2];
#pragma unroll
  for (int m = 0; m < 4; ++m)
#pragma unroll
    for (int ks = 0; ks < 2; ++ks)
      af[m][ks] = *(const short8*)&As[ks * 8192 + (wave * 64 + m * 16 + fr) * 32 + ko];
#pragma unroll
  for (int n = 0; n < 5; ++n)
#pragma unroll
    for (int ks = 0; ks < 2; ++ks)
      bfv[n][ks] = *(const short8*)&Bs[ks * 2560 + (n * 16 + fr) * 32 + ko];
  f32x4 acc[4][5] = {};
#pragma unroll
  for (int m = 0; m < 4; ++m)
#pragma unroll
    for (int n = 0; n < 5; ++n) {
      acc[m][n] = __builtin_amdgcn_mfma_f32_16x16x32_bf16(af[m][0], bfv[n][0], acc[m][n], 0, 0, 0);
      acc[m][n] = __builtin_amdgcn_mfma_f32_16x16x32_bf16(af[m][1], bfv[n][1], acc[m][n], 0, 0, 0);
    }

  const int qq = lane >> 4;
#pragma unroll
  for (int m = 0; m < 4; ++m) {
    f32x4 rnv;
#pragma unroll
    for (int j = 0; j < 4; ++j) {
      const float nv = __shfl(acc[m][4][j], lane & 48);
      rnv[j] = 1.f / (nv + 1e-6f);
    }
    const size_t row = qrow0 + wave * 64 + m * 16 + qq * 4;
#pragma unroll
    for (int n = 0; n < 4; ++n)
#pragma unroll
      for (int j = 0; j < 4; ++j)
        att[(row + j) * 1024 + h * 64 + n * 16 + fr] = f2bf(acc[m][n][j] * rnv[j]);
  }
}

extern "C" void kernel_launch(void* const* d_in, const int* in_sizes, int n_in,
                              void* d_out, int out_size, void* d_ws, size_t ws_size,
                              hipStream_t stream) {
  const float* x = (const float*)d_in[0];      // [4,4096,1024]
  const float* wqkv = (const float*)d_in[1];   // [3072,1024]
  const float* wout = (const float*)d_in[2];   // [1024,1024]
  float* out = (float*)d_out;                  // [4,4096,1024] fp32

  char* ws = (char*)d_ws;
  size_t off = 0;
  auto alloc = [&](size_t bytes) -> void* {
    void* p = ws + off;
    off += (bytes + 255) & ~(size_t)255;
    return p;
  };
  unsigned short* xbf    = (unsigned short*)alloc((size_t)16384 * 1024 * 2);  // 33.5 MB
  unsigned short* wqkvbf = (unsigned short*)alloc((size_t)3072 * 1024 * 2);   //  6.3 MB
  unsigned short* woutbf = (unsigned short*)alloc((size_t)1024 * 1024 * 2);   //  2.1 MB
  unsigned short* big    = (unsigned short*)alloc((size_t)16384 * 2048 * 2);  // 67.1 MB (k|v, later q+att)
  float* kvp = (float*)alloc((size_t)SEG * 64 * 4096 * 4);                    // 16.8 MB
  float* ksp = (float*)alloc((size_t)SEG * 64 * 64 * 4);
  unsigned short* kvb = (unsigned short*)alloc((size_t)64 * 80 * 64 * 2);     // 0.66 MB
  unsigned short* qbuf = big;                          // reuse after kv_partial consumed k,v
  unsigned short* att  = big + (size_t)16384 * 1024;   // second half of big

  cast_f32_bf16<<<2048, 256, 0, stream>>>(x, xbf, 16384 * 1024 / 4);
  cast_f32_bf16<<<1024, 256, 0, stream>>>(wqkv, wqkvbf, 3072 * 1024 / 4);
  cast_f32_bf16<<<512, 256, 0, stream>>>(wout, woutbf, 1024 * 1024 / 4);

  // GEMM1a: [k|v] = x @ w_qkv[1024:3072].T ; fm on k cols (<1024)
  gemm_v4<unsigned short><<<dim3(2048 / 128, 16384 / 256), 512, 0, stream>>>(
      xbf, wqkvbf + (size_t)1024 * 1024, big, 16384, 2048, 1024, 2048, 1024);

  kv_partial<<<64 * SEG, 256, 0, stream>>>(big, kvp, ksp);
  kv_reduce_bf<<<1280, 256, 0, stream>>>(kvp, ksp, kvb);

  // GEMM1b: q = fm(x @ w_qkv[0:1024].T)  (overwrites dead k/v region)
  gemm_v4<unsigned short><<<dim3(1024 / 128, 16384 / 256), 512, 0, stream>>>(
      xbf, wqkvbf, qbuf, 16384, 1024, 1024, 1024, 1024);

  attn_mfma<<<64 * 16, 256, 0, stream>>>(qbuf, kvb, att);

  // GEMM2: out = att @ w_out.T (fp32 out, no fm)
  gemm_v4<float><<<dim3(1024 / 128, 16384 / 256), 512, 0, stream>>>(
      att, woutbf, out, 16384, 1024, 1024, 1024, 0);
}

// Round 8
// 264.242 us; speedup vs baseline: 1.0316x; 1.0316x over previous
//
#include <hip/hip_runtime.h>
#include <hip/hip_bf16.h>
#include <stdint.h>

typedef __attribute__((ext_vector_type(8))) short short8;
typedef __attribute__((ext_vector_type(4))) float f32x4;
typedef __attribute__((ext_vector_type(4))) unsigned short ushort4_t;

#define SEG 16

__device__ __forceinline__ float bf2f(unsigned short u) {
  unsigned int x = ((unsigned int)u) << 16;
  return __uint_as_float(x);
}
__device__ __forceinline__ unsigned short f2bf(float f) {
  unsigned int u = __float_as_uint(f);
  u += 0x7fffu + ((u >> 16) & 1u);
  return (unsigned short)(u >> 16);
}

// async global->LDS, 16B per lane, dest = wave-uniform base + lane*16
__device__ __forceinline__ void gload16(const unsigned short* g, unsigned short* l) {
  __builtin_amdgcn_global_load_lds(
      (const __attribute__((address_space(1))) void*)g,
      (__attribute__((address_space(3))) void*)l, 16, 0, 0);
}

#define MIDBAR() do { __builtin_amdgcn_sched_barrier(0); __builtin_amdgcn_s_barrier(); } while (0)
#define ENDBAR() do { __builtin_amdgcn_s_barrier(); __builtin_amdgcn_sched_barrier(0); } while (0)
#define ENDBARV4() do { asm volatile("s_waitcnt vmcnt(4)" ::: "memory"); \
                        __builtin_amdgcn_s_barrier(); __builtin_amdgcn_sched_barrier(0); } while (0)

// ---------------- cast fp32 -> bf16 (vectorized) ----------------
__global__ void cast_f32_bf16(const float* __restrict__ in,
                              unsigned short* __restrict__ out, int n4) {
  const int stride = gridDim.x * blockDim.x;
  for (int i = blockIdx.x * blockDim.x + threadIdx.x; i < n4; i += stride) {
    const float4 v = ((const float4*)in)[i];
    ushort4_t o;
    o[0] = f2bf(v.x); o[1] = f2bf(v.y); o[2] = f2bf(v.z); o[3] = f2bf(v.w);
    ((ushort4_t*)out)[i] = o;
  }
}

// ======== GEMM v4 (for M=16384,N=2048): 256x128, BK=32, triple-buffer,
// 1 barrier/tile, 2 blocks/CU. Best measured engine for the wide GEMM (84us).
template <typename OutT>
__global__ __launch_bounds__(512, 4) void gemm_v4(
    const unsigned short* __restrict__ A, const unsigned short* __restrict__ Bm,
    OutT* __restrict__ C, int M, int N, int K, int ldc, int fm_cols) {
  __shared__ unsigned short lds[3 * 12288];  // slot: A @0 (8192 el), B @8192 (4096 el)
  const int tid = threadIdx.x;
  const int lane = tid & 63;
  const int w = tid >> 6;
  const int wr = w >> 1, wc = w & 1;  // 4x2 wave grid; wave out = 64x64
  const int gx = gridDim.x;
  const int nwg = gx * gridDim.y;
  const int hwid = blockIdx.y * gx + blockIdx.x;
  const int cpx = nwg >> 3;
  const int L = (hwid & 7) * cpx + (hwid >> 3);
  const int bx = L % gx, by = L / gx;
  const size_t arow0 = (size_t)by * 256;
  const size_t bcol0 = (size_t)bx * 128;
  const int nt = K >> 5;  // BK=32

  const int rl = lane >> 2;
  const int sce = (((lane & 3) ^ (rl & 3) ^ ((rl >> 2) & 1)) << 3);  // pre-swizzled src
  const unsigned short* Ab0 = A + (arow0 + w * 16 + rl) * K + sce;
  const unsigned short* Ab1 = A + (arow0 + 128 + w * 16 + rl) * K + sce;
  const unsigned short* Bb0 = Bm + (bcol0 + w * 16 + rl) * K + sce;

  auto stage = [&](int kt, unsigned short* buf) {
    const int k0 = (kt < nt ? kt : kt - nt) << 5;  // wrap = harmless dummy restage
    gload16(Ab0 + k0, buf + w * 512);
    gload16(Ab1 + k0, buf + 4096 + w * 512);
    gload16(Bb0 + k0, buf + 8192 + w * 512);
  };

  f32x4 acc[4][4] = {};
  const int fr = lane & 15;
  const int kc = lane >> 4;

  auto rdA = [&](const unsigned short* buf, int mm) {
    const int r = wr * 64 + mm * 16 + fr;
    return *(const short8*)&buf[r * 32 + ((kc ^ (fr & 3) ^ ((fr >> 2) & 1)) << 3)];
  };
  auto rdB = [&](const unsigned short* buf, int nn) {
    const int r = wc * 64 + nn * 16 + fr;
    return *(const short8*)&buf[8192 + r * 32 + ((kc ^ (fr & 3) ^ ((fr >> 2) & 1)) << 3)];
  };

  stage(0, lds);
  stage(1, lds + 12288);
  asm volatile("s_waitcnt vmcnt(3)" ::: "memory");
  __builtin_amdgcn_s_barrier();
  __builtin_amdgcn_sched_barrier(0);

  for (int t = 0; t < nt; ++t) {
    const unsigned short* cur = lds + (t % 3) * 12288;
    unsigned short* nxt = lds + ((t + 2) % 3) * 12288;
    stage(t + 2, nxt);
    const short8 af0 = rdA(cur, 0), af1 = rdA(cur, 1), af2 = rdA(cur, 2), af3 = rdA(cur, 3);
    const short8 bf0 = rdB(cur, 0), bf1 = rdB(cur, 1), bf2 = rdB(cur, 2), bf3 = rdB(cur, 3);
    __builtin_amdgcn_s_setprio(1);
    acc[0][0] = __builtin_amdgcn_mfma_f32_16x16x32_bf16(af0, bf0, acc[0][0], 0, 0, 0);
    acc[0][1] = __builtin_amdgcn_mfma_f32_16x16x32_bf16(af0, bf1, acc[0][1], 0, 0, 0);
    acc[1][0] = __builtin_amdgcn_mfma_f32_16x16x32_bf16(af1, bf0, acc[1][0], 0, 0, 0);
    acc[1][1] = __builtin_amdgcn_mfma_f32_16x16x32_bf16(af1, bf1, acc[1][1], 0, 0, 0);
    acc[0][2] = __builtin_amdgcn_mfma_f32_16x16x32_bf16(af0, bf2, acc[0][2], 0, 0, 0);
    acc[0][3] = __builtin_amdgcn_mfma_f32_16x16x32_bf16(af0, bf3, acc[0][3], 0, 0, 0);
    acc[1][2] = __builtin_amdgcn_mfma_f32_16x16x32_bf16(af1, bf2, acc[1][2], 0, 0, 0);
    acc[1][3] = __builtin_amdgcn_mfma_f32_16x16x32_bf16(af1, bf3, acc[1][3], 0, 0, 0);
    acc[2][0] = __builtin_amdgcn_mfma_f32_16x16x32_bf16(af2, bf0, acc[2][0], 0, 0, 0);
    acc[2][1] = __builtin_amdgcn_mfma_f32_16x16x32_bf16(af2, bf1, acc[2][1], 0, 0, 0);
    acc[3][0] = __builtin_amdgcn_mfma_f32_16x16x32_bf16(af3, bf0, acc[3][0], 0, 0, 0);
    acc[3][1] = __builtin_amdgcn_mfma_f32_16x16x32_bf16(af3, bf1, acc[3][1], 0, 0, 0);
    acc[2][2] = __builtin_amdgcn_mfma_f32_16x16x32_bf16(af2, bf2, acc[2][2], 0, 0, 0);
    acc[2][3] = __builtin_amdgcn_mfma_f32_16x16x32_bf16(af2, bf3, acc[2][3], 0, 0, 0);
    acc[3][2] = __builtin_amdgcn_mfma_f32_16x16x32_bf16(af3, bf2, acc[3][2], 0, 0, 0);
    acc[3][3] = __builtin_amdgcn_mfma_f32_16x16x32_bf16(af3, bf3, acc[3][3], 0, 0, 0);
    __builtin_amdgcn_s_setprio(0);
    asm volatile("s_waitcnt vmcnt(3)" ::: "memory");
    __builtin_amdgcn_s_barrier();
    __builtin_amdgcn_sched_barrier(0);
  }

  const int qq = lane >> 4;
#pragma unroll
  for (int m = 0; m < 4; ++m) {
#pragma unroll
    for (int n = 0; n < 4; ++n) {
      const int col = (int)bcol0 + wc * 64 + n * 16 + fr;
      const bool dofm = col < fm_cols;
#pragma unroll
      for (int j = 0; j < 4; ++j) {
        const int row = (int)arow0 + wr * 64 + m * 16 + qq * 4 + j;
        float x = acc[m][n][j];
        if (dofm) x = (x > 0.f) ? x + 1.f : __expf(x);
        if constexpr (sizeof(OutT) == 2) {
          C[(size_t)row * ldc + col] = (OutT)f2bf(x);
        } else {
          C[(size_t)row * ldc + col] = x;
        }
      }
    }
  }
}

// ======== gemm8p (for N=1024 GEMMs): 256x256, BK=64, 8-phase (R5, validated
// ~50us at M=16384,N=1024,K=1024 — halves staged bytes vs 256x128). ========
template <typename OutT>
__global__ __launch_bounds__(512, 2) void gemm8p(
    const unsigned short* __restrict__ A, const unsigned short* __restrict__ Bm,
    OutT* __restrict__ C, int M, int N, int K, int ldc, int fm_cols) {
  __shared__ unsigned short lds[65536];  // 128KB
  unsigned short* A0 = lds;
  unsigned short* B0 = lds + 16384;
  unsigned short* A1 = lds + 32768;
  unsigned short* B1 = lds + 49152;
  const int tid = threadIdx.x;
  const int lane = tid & 63;
  const int w = tid >> 6;
  const int wr = w >> 2, wc = w & 3;     // 2x4 wave grid; wave out = 128x64
  const int gx = gridDim.x;
  const int nwg = gx * gridDim.y;
  const int hwid = blockIdx.y * gx + blockIdx.x;
  const int cpx = nwg >> 3;
  const int L = (hwid & 7) * cpx + (hwid >> 3);
  const int bx = L % gx, by = L / gx;
  const size_t arow0 = (size_t)by * 256;
  const size_t bcol0 = (size_t)bx * 256;
  const int nt = K >> 6;                 // BK=64
  const int nit = nt >> 1;

  const int sc8 = ((lane & 7) ^ (lane >> 3)) << 3;
  const unsigned short* Abase = A + (arow0 + (lane >> 3)) * K + sc8;
  const unsigned short* Bbase = Bm + (bcol0 + (lane >> 3)) * K + sc8;

  auto stage = [&](int kt, const unsigned short* mb, unsigned short* region, int half) {
    const int ktw = (kt >= nt) ? kt - nt : kt;
    const int rb = half * 128 + w * 16;
    const unsigned short* s = mb + (size_t)rb * K + ktw * 64;
    gload16(s, region + rb * 64);
    gload16(s + (size_t)8 * K, region + (rb + 8) * 64);
  };

  short8 af[4][2];
  short8 bfv[4][2];
  f32x4 acc[8][4] = {};
  const int fr = lane & 15;
  const int kc = lane >> 4;

  auto readA = [&](const unsigned short* bufA, int mh) {
#pragma unroll
    for (int mm = 0; mm < 4; ++mm) {
      const int r = wr * 128 + (mh * 4 + mm) * 16 + fr;
#pragma unroll
      for (int ks = 0; ks < 2; ++ks)
        af[mm][ks] = *(const short8*)&bufA[r * 64 + (((ks * 4 + kc) ^ (fr & 7)) << 3)];
    }
  };
  auto readB = [&](const unsigned short* bufB, int nh) {
#pragma unroll
    for (int nn = 0; nn < 2; ++nn) {
      const int n = nh * 2 + nn;
      const int r = wc * 64 + n * 16 + fr;
#pragma unroll
      for (int ks = 0; ks < 2; ++ks)
        bfv[n][ks] = *(const short8*)&bufB[r * 64 + (((ks * 4 + kc) ^ (fr & 7)) << 3)];
    }
  };
  auto quad = [&](int mh, int nh) {
    __builtin_amdgcn_s_setprio(1);
#pragma unroll
    for (int mm = 0; mm < 4; ++mm)
#pragma unroll
      for (int nn = 0; nn < 2; ++nn) {
        f32x4& a = acc[mh * 4 + mm][nh * 2 + nn];
        a = __builtin_amdgcn_mfma_f32_16x16x32_bf16(af[mm][0], bfv[nh * 2 + nn][0], a, 0, 0, 0);
        a = __builtin_amdgcn_mfma_f32_16x16x32_bf16(af[mm][1], bfv[nh * 2 + nn][1], a, 0, 0, 0);
      }
    __builtin_amdgcn_s_setprio(0);
  };

  stage(0, Abase, A0, 0); stage(0, Abase, A0, 1);
  stage(0, Bbase, B0, 0); stage(0, Bbase, B0, 1);
  stage(1, Bbase, B1, 0); stage(1, Bbase, B1, 1);
  asm volatile("s_waitcnt vmcnt(0)" ::: "memory");
  __builtin_amdgcn_s_barrier();
  __builtin_amdgcn_sched_barrier(0);

  for (int i2 = 0; i2 < nit; ++i2) {
    const int t0 = i2 * 2;
    readA(A0, 0); readB(B0, 0);
    stage(t0 + 1, Abase, A1, 0);
    MIDBAR(); quad(0, 0); ENDBAR();          // q0

    readB(B0, 1);
    stage(t0 + 1, Abase, A1, 1);
    MIDBAR(); quad(0, 1); ENDBAR();          // q1

    readA(A0, 1);
    stage(t0 + 2, Bbase, B0, 0);
    MIDBAR(); quad(1, 0); ENDBAR();          // q2

    stage(t0 + 2, Bbase, B0, 1);
    MIDBAR(); quad(1, 1); ENDBARV4();        // q3

    readA(A1, 0); readB(B1, 0);
    stage(t0 + 2, Abase, A0, 0);
    MIDBAR(); quad(0, 0); ENDBAR();          // q4

    readB(B1, 1);
    stage(t0 + 2, Abase, A0, 1);
    MIDBAR(); quad(0, 1); ENDBAR();          // q5

    readA(A1, 1);
    stage(t0 + 3, Bbase, B1, 0);
    MIDBAR(); quad(1, 0); ENDBAR();          // q6

    stage(t0 + 3, Bbase, B1, 1);
    MIDBAR(); quad(1, 1); ENDBARV4();        // q7
  }

  const int qq = lane >> 4;
#pragma unroll
  for (int m = 0; m < 8; ++m) {
#pragma unroll
    for (int n = 0; n < 4; ++n) {
      const int col = (int)bcol0 + wc * 64 + n * 16 + fr;
      const bool dofm = col < fm_cols;
#pragma unroll
      for (int j = 0; j < 4; ++j) {
        const int row = (int)arow0 + wr * 128 + m * 16 + qq * 4 + j;
        float x = acc[m][n][j];
        if (dofm) x = (x > 0.f) ? x + 1.f : __expf(x);
        if constexpr (sizeof(OutT) == 2) {
          C[(size_t)row * ldc + col] = (OutT)f2bf(x);
        } else {
          C[(size_t)row * ldc + col] = x;
        }
      }
    }
  }
}

// ---------------- kv state partials: kv[bh,d,e] = sum_n k[n,d]*v[n,e] ----------------
__global__ __launch_bounds__(256) void kv_partial(
    const unsigned short* __restrict__ kvmat, float* __restrict__ kvp,
    float* __restrict__ ksp) {
  const int blk = blockIdx.x;
  const int bh = blk >> 4;
  const int seg = blk & (SEG - 1);
  const int b = bh >> 4, h = bh & 15;
  const int rows = 4096 / SEG;
  const size_t row0 = (size_t)b * 4096 + (size_t)seg * rows;
  const unsigned short* kb = kvmat + row0 * 2048 + h * 64;
  const unsigned short* vb = kvmat + row0 * 2048 + 1024 + h * 64;
  __shared__ float kl[32][64];
  __shared__ float vl[32][64];
  const int tid = threadIdx.x;
  const int d0 = (tid >> 4) * 4, e0 = (tid & 15) * 4;
  const int lr = tid >> 3, lc = (tid & 7) * 8;
  float accm[4][4] = {};
  float ksacc[4] = {0.f, 0.f, 0.f, 0.f};

  for (int c = 0; c < rows; c += 32) {
    __syncthreads();
    {
      const short8 k8 = *(const short8*)(kb + (size_t)(c + lr) * 2048 + lc);
      const short8 v8 = *(const short8*)(vb + (size_t)(c + lr) * 2048 + lc);
#pragma unroll
      for (int j = 0; j < 8; ++j) {
        kl[lr][lc + j] = bf2f((unsigned short)k8[j]);
        vl[lr][lc + j] = bf2f((unsigned short)v8[j]);
      }
    }
    __syncthreads();
#pragma unroll
    for (int r = 0; r < 32; ++r) {
      const f32x4 kd = *(const f32x4*)&kl[r][d0];
      const f32x4 ve = *(const f32x4*)&vl[r][e0];
#pragma unroll
      for (int i = 0; i < 4; ++i) {
        ksacc[i] += kd[i];
#pragma unroll
        for (int j = 0; j < 4; ++j) accm[i][j] += kd[i] * ve[j];
      }
    }
  }
  float* kvout = kvp + ((size_t)seg * 64 + bh) * 4096;
#pragma unroll
  for (int i = 0; i < 4; ++i) {
    f32x4 o = {accm[i][0], accm[i][1], accm[i][2], accm[i][3]};
    *(f32x4*)&kvout[(d0 + i) * 64 + e0] = o;
  }
  if ((tid & 15) == 0) {
#pragma unroll
    for (int i = 0; i < 4; ++i)
      ksp[((size_t)seg * 64 + bh) * 64 + d0 + i] = ksacc[i];
  }
}

// reduce partials -> kvb[bh][80][64] bf16: rows e<64 = kv^T, row 64 = ksum, 65..79 = 0
__global__ void kv_reduce_bf(const float* __restrict__ kvp, const float* __restrict__ ksp,
                             unsigned short* __restrict__ kvb) {
  const int idx = blockIdx.x * 256 + threadIdx.x;
  if (idx >= 64 * 80 * 64) return;
  const int bh = idx / 5120, r = idx % 5120, e = r >> 6, d = r & 63;
  float s = 0.f;
  if (e < 64) {
    for (int g = 0; g < SEG; ++g) s += kvp[((size_t)g * 64 + bh) * 4096 + d * 64 + e];
  } else if (e == 64) {
    for (int g = 0; g < SEG; ++g) s += ksp[((size_t)g * 64 + bh) * 64 + d];
  }
  kvb[idx] = f2bf(s);
}

// ---------------- attn via MFMA: att[row, h*64+e] = (q.kv)/(q.ksum + 1e-6) ----------------
__global__ __launch_bounds__(256) void attn_mfma(
    const unsigned short* __restrict__ q,
    const unsigned short* __restrict__ kvb,
    unsigned short* __restrict__ att) {
  const int bh = blockIdx.x >> 4;
  const int rt = blockIdx.x & 15;
  const int b = bh >> 4, h = bh & 15;
  __shared__ unsigned short As[2 * 256 * 32];
  __shared__ unsigned short Bs[2 * 80 * 32];
  const int tid = threadIdx.x, lane = tid & 63, wave = tid >> 6;
  const int l4 = lane >> 2;
  const int c8 = (lane & 3) * 8;
  const size_t qrow0 = (size_t)b * 4096 + (size_t)rt * 256;
  const unsigned short* Ab = q + (qrow0 + wave * 64 + l4) * 1024 + h * 64 + c8;
  unsigned short* AsW = As;
#pragma unroll
  for (int ks = 0; ks < 2; ++ks)
#pragma unroll
    for (int i = 0; i < 4; ++i)
      gload16(Ab + (size_t)i * 16 * 1024 + ks * 32,
              AsW + ks * 8192 + wave * 2048 + i * 512);
  for (int c = tid; c < 640; c += 256) {
    const int m0 = c * 8, ks = m0 / 2560, rr = m0 % 2560, e = rr / 32, dk = rr % 32;
    *(short8*)&Bs[m0] = *(const short8*)&kvb[(size_t)bh * 5120 + e * 64 + ks * 32 + dk];
  }
  __syncthreads();

  const int fr = lane & 15, ko = (lane >> 4) * 8;
  short8 af[4][2], bfv[5][2];
#pragma unroll
  for (int m = 0; m < 4; ++m)
#pragma unroll
    for (int ks = 0; ks < 2; ++ks)
      af[m][ks] = *(const short8*)&As[ks * 8192 + (wave * 64 + m * 16 + fr) * 32 + ko];
#pragma unroll
  for (int n = 0; n < 5; ++n)
#pragma unroll
    for (int ks = 0; ks < 2; ++ks)
      bfv[n][ks] = *(const short8*)&Bs[ks * 2560 + (n * 16 + fr) * 32 + ko];
  f32x4 acc[4][5] = {};
#pragma unroll
  for (int m = 0; m < 4; ++m)
#pragma unroll
    for (int n = 0; n < 5; ++n) {
      acc[m][n] = __builtin_amdgcn_mfma_f32_16x16x32_bf16(af[m][0], bfv[n][0], acc[m][n], 0, 0, 0);
      acc[m][n] = __builtin_amdgcn_mfma_f32_16x16x32_bf16(af[m][1], bfv[n][1], acc[m][n], 0, 0, 0);
    }

  const int qq = lane >> 4;
#pragma unroll
  for (int m = 0; m < 4; ++m) {
    f32x4 rnv;
#pragma unroll
    for (int j = 0; j < 4; ++j) {
      const float nv = __shfl(acc[m][4][j], lane & 48);
      rnv[j] = 1.f / (nv + 1e-6f);
    }
    const size_t row = qrow0 + wave * 64 + m * 16 + qq * 4;
#pragma unroll
    for (int n = 0; n < 4; ++n)
#pragma unroll
      for (int j = 0; j < 4; ++j)
        att[(row + j) * 1024 + h * 64 + n * 16 + fr] = f2bf(acc[m][n][j] * rnv[j]);
  }
}

extern "C" void kernel_launch(void* const* d_in, const int* in_sizes, int n_in,
                              void* d_out, int out_size, void* d_ws, size_t ws_size,
                              hipStream_t stream) {
  const float* x = (const float*)d_in[0];      // [4,4096,1024]
  const float* wqkv = (const float*)d_in[1];   // [3072,1024]
  const float* wout = (const float*)d_in[2];   // [1024,1024]
  float* out = (float*)d_out;                  // [4,4096,1024] fp32

  char* ws = (char*)d_ws;
  size_t off = 0;
  auto alloc = [&](size_t bytes) -> void* {
    void* p = ws + off;
    off += (bytes + 255) & ~(size_t)255;
    return p;
  };
  unsigned short* xbf    = (unsigned short*)alloc((size_t)16384 * 1024 * 2);
  unsigned short* wqkvbf = (unsigned short*)alloc((size_t)3072 * 1024 * 2);
  unsigned short* woutbf = (unsigned short*)alloc((size_t)1024 * 1024 * 2);
  unsigned short* big    = (unsigned short*)alloc((size_t)16384 * 2048 * 2);
  float* kvp = (float*)alloc((size_t)SEG * 64 * 4096 * 4);
  float* ksp = (float*)alloc((size_t)SEG * 64 * 64 * 4);
  unsigned short* kvb = (unsigned short*)alloc((size_t)64 * 80 * 64 * 2);
  unsigned short* qbuf = big;
  unsigned short* att  = big + (size_t)16384 * 1024;

  cast_f32_bf16<<<2048, 256, 0, stream>>>(x, xbf, 16384 * 1024 / 4);
  cast_f32_bf16<<<1024, 256, 0, stream>>>(wqkv, wqkvbf, 3072 * 1024 / 4);
  cast_f32_bf16<<<512, 256, 0, stream>>>(wout, woutbf, 1024 * 1024 / 4);

  // GEMM1a: [k|v] = x @ w_qkv[1024:3072].T ; fm on k cols (<1024)  [v4 engine]
  gemm_v4<unsigned short><<<dim3(2048 / 128, 16384 / 256), 512, 0, stream>>>(
      xbf, wqkvbf + (size_t)1024 * 1024, big, 16384, 2048, 1024, 2048, 1024);

  kv_partial<<<64 * SEG, 256, 0, stream>>>(big, kvp, ksp);
  kv_reduce_bf<<<1280, 256, 0, stream>>>(kvp, ksp, kvb);

  // GEMM1b: q = fm(x @ w_qkv[0:1024].T)  [8-phase 256^2 engine]
  gemm8p<unsigned short><<<dim3(1024 / 256, 16384 / 256), 512, 0, stream>>>(
      xbf, wqkvbf, qbuf, 16384, 1024, 1024, 1024, 1024);

  attn_mfma<<<64 * 16, 256, 0, stream>>>(qbuf, kvb, att);

  // GEMM2: out = att @ w_out.T  [8-phase 256^2 engine]
  gemm8p<float><<<dim3(1024 / 256, 16384 / 256), 512, 0, stream>>>(
      att, woutbf, out, 16384, 1024, 1024, 1024, 0);
}